// Round 1
// baseline (329.712 us; speedup 1.0000x reference)
//
#include <hip/hip_runtime.h>
#include <math.h>

// IdealScore: B=16, N=10000, D=3072, fp32.
//   arg[b][n] = (at/bt2)*dot(x_b, img_n) - ((1-sval)/(2*sval))*||img_n||^2
//   (x_sq dropped: softmax shift-invariant per row)
//   w = softmax_n(arg); mix = w @ imgs; out = (at*mix - x)/bt2
#define BB 16
#define NN 10000
#define DD 3072

#define DC1 256          // K1 D-chunk (floats)

#define NT3 224          // K3 n-tile per block
#define NCH3 45          // 45*224 = 10080 >= 10000
#define DC3 512          // K3 d-chunk (128 thr * float4)

// ---------------- K1: args = scaled cross-GEMM + i_sq term ----------------
// grid 625 x 256 threads (4 waves). Wave w of block blk owns image rows
// n0 = blk*16 + w*4 .. +3, lanes stride D with float4 (coalesced).
// x (16x3072, 196 KB) staged chunk-wise in LDS; reads are the canonical
// contiguous-float4 pattern -> conflict-free.
__global__ __launch_bounds__(256) void k1_args(
    const float* __restrict__ x, const float* __restrict__ images,
    const float* __restrict__ svalp, float* __restrict__ args)
{
  __shared__ float xs[BB * DC1];            // 16 KB
  const int t = threadIdx.x;
  const int lane = t & 63;
  const int wave = t >> 6;
  const int n0 = blockIdx.x * 16 + wave * 4;   // 625*16 = 10000 exactly

  float dotv[4][BB];
  float isq[4];
#pragma unroll
  for (int r = 0; r < 4; ++r) {
    isq[r] = 0.f;
#pragma unroll
    for (int b = 0; b < BB; ++b) dotv[r][b] = 0.f;
  }

  for (int c = 0; c < DD / DC1; ++c) {
    __syncthreads();
    // stage x[:, c*256 .. +255] into LDS: 4096 floats = 1024 float4
#pragma unroll
    for (int k = 0; k < 4; ++k) {
      int f = t + 256 * k;                   // float4 index
      int row = f >> 6;                      // 64 float4 per row
      int col = (f & 63) << 2;
      *(float4*)&xs[row * DC1 + col] =
          *(const float4*)&x[row * DD + c * DC1 + col];
    }
    __syncthreads();

    const int dg = c * DC1 + (lane << 2);
    float4 im[4];
#pragma unroll
    for (int r = 0; r < 4; ++r)
      im[r] = *(const float4*)&images[(size_t)(n0 + r) * DD + dg];
#pragma unroll
    for (int r = 0; r < 4; ++r)
      isq[r] += im[r].x * im[r].x + im[r].y * im[r].y +
                im[r].z * im[r].z + im[r].w * im[r].w;
#pragma unroll
    for (int b = 0; b < BB; ++b) {
      float4 xv = *(const float4*)&xs[b * DC1 + (lane << 2)];
#pragma unroll
      for (int r = 0; r < 4; ++r)
        dotv[r][b] += im[r].x * xv.x + im[r].y * xv.y +
                      im[r].z * xv.z + im[r].w * xv.w;
    }
  }

  // 64-lane butterfly reductions (all lanes end with the full sum)
#pragma unroll
  for (int r = 0; r < 4; ++r) {
#pragma unroll
    for (int b = 0; b < BB; ++b) {
      float v = dotv[r][b];
#pragma unroll
      for (int m = 32; m >= 1; m >>= 1) v += __shfl_xor(v, m, 64);
      dotv[r][b] = v;
    }
    float v = isq[r];
#pragma unroll
    for (int m = 32; m >= 1; m >>= 1) v += __shfl_xor(v, m, 64);
    isq[r] = v;
  }

  const float sval = *svalp;
  const float at = sqrtf(1.f - sval);
  const float c1 = at / sval;                    // at / bt2
  const float c2 = (1.f - sval) / (2.f * sval);  // at^2 / (2*bt2)

  if (lane < BB) {
#pragma unroll
    for (int r = 0; r < 4; ++r) {
      float dv = dotv[r][0];
#pragma unroll
      for (int b = 1; b < BB; ++b)
        if (lane == b) dv = dotv[r][b];          // cndmask chain
      args[lane * NN + (n0 + r)] = c1 * dv - c2 * isq[r];
    }
  }
}

// ---------------- K2: per-row softmax stats (m, l) ----------------
__global__ __launch_bounds__(256) void k2_stats(
    const float* __restrict__ args, float* __restrict__ mout,
    float* __restrict__ lout)
{
  __shared__ float red[4];
  const int b = blockIdx.x;
  const int t = threadIdx.x;
  const int lane = t & 63, wave = t >> 6;

  float mx = -INFINITY;
  for (int n = t; n < NN; n += 256) mx = fmaxf(mx, args[b * NN + n]);
#pragma unroll
  for (int m = 32; m >= 1; m >>= 1) mx = fmaxf(mx, __shfl_xor(mx, m, 64));
  if (lane == 0) red[wave] = mx;
  __syncthreads();
  mx = fmaxf(fmaxf(red[0], red[1]), fmaxf(red[2], red[3]));
  __syncthreads();

  float s = 0.f;
  for (int n = t; n < NN; n += 256) s += __expf(args[b * NN + n] - mx);
#pragma unroll
  for (int m = 32; m >= 1; m >>= 1) s += __shfl_xor(s, m, 64);
  if (lane == 0) red[wave] = s;
  __syncthreads();
  if (t == 0) {
    mout[b] = mx;
    lout[b] = red[0] + red[1] + red[2] + red[3];
  }
}

// ---------------- K3: partial mix = w @ imgs over an n-chunk ----------------
// grid (6 d-chunks, 45 n-chunks) x 128 threads. Weights for the n-tile staged
// in LDS (broadcast reads); one coalesced float4 image load per n per thread.
__global__ __launch_bounds__(128) void k3_partial(
    const float* __restrict__ images, const float* __restrict__ args,
    const float* __restrict__ m, const float* __restrict__ l,
    float* __restrict__ partial)
{
  __shared__ float w[BB * NT3];              // 14 KB
  const int t = threadIdx.x;
  const int dchunk = blockIdx.x, nchunk = blockIdx.y;
  const int d0 = dchunk * DC3 + (t << 2);

  for (int i = t; i < BB * NT3; i += 128) {
    int b = i / NT3;
    int n = nchunk * NT3 + (i % NT3);
    w[i] = (n < NN) ? __expf(args[b * NN + n] - m[b]) / l[b] : 0.f;
  }
  __syncthreads();

  float4 acc[BB];
#pragma unroll
  for (int b = 0; b < BB; ++b) acc[b] = make_float4(0.f, 0.f, 0.f, 0.f);

  for (int j = 0; j < NT3; ++j) {
    int n = nchunk * NT3 + j;
    if (n >= NN) break;                      // uniform across block
    float4 im = *(const float4*)&images[(size_t)n * DD + d0];
#pragma unroll
    for (int b = 0; b < BB; ++b) {
      float wb = w[b * NT3 + j];             // LDS broadcast
      acc[b].x += wb * im.x; acc[b].y += wb * im.y;
      acc[b].z += wb * im.z; acc[b].w += wb * im.w;
    }
  }
#pragma unroll
  for (int b = 0; b < BB; ++b)
    *(float4*)&partial[((size_t)nchunk * BB + b) * DD + d0] = acc[b];
}

// ---------------- K4: reduce partials + final affine ----------------
__global__ __launch_bounds__(256) void k4_out(
    const float* __restrict__ x, const float* __restrict__ partial,
    const float* __restrict__ svalp, float* __restrict__ out)
{
  const int g = blockIdx.x * 256 + threadIdx.x;
  const int i = g << 2;                      // flat float index in [B*D]
  const float sval = *svalp;
  const float at = sqrtf(1.f - sval);
  const float inv_bt2 = 1.f / sval;

  float4 s = make_float4(0.f, 0.f, 0.f, 0.f);
  for (int c = 0; c < NCH3; ++c) {
    float4 p = *(const float4*)&partial[(size_t)c * BB * DD + i];
    s.x += p.x; s.y += p.y; s.z += p.z; s.w += p.w;
  }
  float4 xv = *(const float4*)&x[i];
  float4 o;
  o.x = (at * s.x - xv.x) * inv_bt2;
  o.y = (at * s.y - xv.y) * inv_bt2;
  o.z = (at * s.z - xv.z) * inv_bt2;
  o.w = (at * s.w - xv.w) * inv_bt2;
  *(float4*)&out[i] = o;
}

extern "C" void kernel_launch(void* const* d_in, const int* in_sizes, int n_in,
                              void* d_out, int out_size, void* d_ws, size_t ws_size,
                              hipStream_t stream) {
  const float* x      = (const float*)d_in[0];
  const float* images = (const float*)d_in[1];
  const float* sval   = (const float*)d_in[2];
  float* out = (float*)d_out;
  float* ws  = (float*)d_ws;

  // ws layout (floats): args[16*10000] | m[16] | l[16] | partial[45*16*3072]
  // total = 160032 + 2211840 = 2,371,872 floats = 9.49 MB
  float* args    = ws;
  float* mbuf    = ws + 160000;
  float* lbuf    = ws + 160016;
  float* partial = ws + 160032;

  hipLaunchKernelGGL(k1_args, dim3(625), dim3(256), 0, stream,
                     x, images, sval, args);
  hipLaunchKernelGGL(k2_stats, dim3(16), dim3(256), 0, stream,
                     args, mbuf, lbuf);
  hipLaunchKernelGGL(k3_partial, dim3(6, NCH3), dim3(128), 0, stream,
                     images, args, mbuf, lbuf, partial);
  hipLaunchKernelGGL(k4_out, dim3(48), dim3(256), 0, stream,
                     x, partial, sval, out);
}

// Round 2
// 227.538 us; speedup vs baseline: 1.4490x; 1.4490x over previous
//
#include <hip/hip_runtime.h>
#include <math.h>

// IdealScore: B=16, N=10000, D=3072, fp32.
//   arg[b][n] = (at/bt2)*dot(x_b, img_n) - ((1-sval)/(2*sval))*||img_n||^2
//   (x_sq dropped: softmax shift-invariant per row)
//   w = softmax_n(arg); mix = w @ imgs; out = (at*mix - x)/bt2
//
// Softmax over N=10000 with arg std ~88 is near-one-hot: rows with
// arg < m-40 have weight <= 4e-18 (contribution < 1e-13, threshold 0.205).
// So pass 2 is a sparse gather over the ~1-5 surviving rows per b.
#define BB 16
#define NN 10000
#define DD 3072
#define SEL_CUT 40.0f

// ---------------- K1: args = scaled cross-GEMM + i_sq term ----------------
// 625 blocks x 256 threads (4 waves). Wave w owns image rows
// n0 = blk*16 + w*4 .. +3; lanes cover D in 12 chunks of 256 floats
// (float4/lane, coalesced). x read straight from global: the 16 KB
// per-chunk x working set is L1-resident; no LDS, no barriers.
__global__ __launch_bounds__(256) void k1_args(
    const float* __restrict__ x, const float* __restrict__ images,
    const float* __restrict__ svalp, float* __restrict__ args)
{
  const int t = threadIdx.x;
  const int lane = t & 63;
  const int wave = t >> 6;
  const int n0 = blockIdx.x * 16 + wave * 4;   // 625*16 = 10000 exactly

  float dotv[4][BB];
  float isq[4];
#pragma unroll
  for (int r = 0; r < 4; ++r) {
    isq[r] = 0.f;
#pragma unroll
    for (int b = 0; b < BB; ++b) dotv[r][b] = 0.f;
  }

#pragma unroll 1
  for (int c = 0; c < DD / 256; ++c) {
    const int dg = c * 256 + (lane << 2);
    float4 im[4];
#pragma unroll
    for (int r = 0; r < 4; ++r)
      im[r] = *(const float4*)&images[(size_t)(n0 + r) * DD + dg];
#pragma unroll
    for (int r = 0; r < 4; ++r)
      isq[r] += im[r].x * im[r].x + im[r].y * im[r].y +
                im[r].z * im[r].z + im[r].w * im[r].w;
#pragma unroll
    for (int b = 0; b < BB; ++b) {
      float4 xv = *(const float4*)&x[b * DD + dg];   // L1-resident
#pragma unroll
      for (int r = 0; r < 4; ++r)
        dotv[r][b] += im[r].x * xv.x + im[r].y * xv.y +
                      im[r].z * xv.z + im[r].w * xv.w;
    }
  }

  // 64-lane butterfly reductions (all lanes end with the full sum)
#pragma unroll
  for (int r = 0; r < 4; ++r) {
#pragma unroll
    for (int b = 0; b < BB; ++b) {
      float v = dotv[r][b];
#pragma unroll
      for (int m = 32; m >= 1; m >>= 1) v += __shfl_xor(v, m, 64);
      dotv[r][b] = v;
    }
    float v = isq[r];
#pragma unroll
    for (int m = 32; m >= 1; m >>= 1) v += __shfl_xor(v, m, 64);
    isq[r] = v;
  }

  const float sval = *svalp;
  const float at = sqrtf(1.f - sval);
  const float c1 = at / sval;                    // at / bt2
  const float c2 = (1.f - sval) / (2.f * sval);  // at^2 / (2*bt2)

  if (lane < BB) {
#pragma unroll
    for (int r = 0; r < 4; ++r) {
      float dv = dotv[r][0];
#pragma unroll
      for (int b = 1; b < BB; ++b)
        if (lane == b) dv = dotv[r][b];          // cndmask chain, no spill
      args[lane * NN + (n0 + r)] = c1 * dv - c2 * isq[r];
    }
  }
}

// ---------- K2: per-row softmax stats + compact surviving (n, w) ----------
// 16 blocks x 1024 threads. Three strided passes over one 40 KB row
// (L1/L2-hot after pass 1): max, sum-exp, select arg > m-40.
__global__ __launch_bounds__(1024) void k2_select(
    const float* __restrict__ args, int* __restrict__ cnt,
    int* __restrict__ idx, float* __restrict__ wv)
{
  __shared__ float red[16];
  __shared__ float mshared, lshared;
  const int b = blockIdx.x;
  const int t = threadIdx.x;
  const int lane = t & 63, wave = t >> 6;
  if (t == 0) cnt[b] = 0;                    // ws is poisoned 0xAA
  const float* row = args + b * NN;

  float mx = -INFINITY;
  for (int n = t; n < NN; n += 1024) mx = fmaxf(mx, row[n]);
#pragma unroll
  for (int m = 32; m >= 1; m >>= 1) mx = fmaxf(mx, __shfl_xor(mx, m, 64));
  if (lane == 0) red[wave] = mx;
  __syncthreads();
  if (wave == 0) {
    float v = (lane < 16) ? red[lane] : -INFINITY;
#pragma unroll
    for (int m = 8; m >= 1; m >>= 1) v = fmaxf(v, __shfl_xor(v, m, 64));
    if (lane == 0) mshared = v;
  }
  __syncthreads();
  mx = mshared;

  float s = 0.f;
  for (int n = t; n < NN; n += 1024) s += __expf(row[n] - mx);
#pragma unroll
  for (int m = 32; m >= 1; m >>= 1) s += __shfl_xor(s, m, 64);
  if (lane == 0) red[wave] = s;
  __syncthreads();
  if (wave == 0) {
    float v = (lane < 16) ? red[lane] : 0.f;
#pragma unroll
    for (int m = 8; m >= 1; m >>= 1) v += __shfl_xor(v, m, 64);
    if (lane == 0) lshared = v;
  }
  __syncthreads();
  const float invl = 1.f / lshared;

  for (int n = t; n < NN; n += 1024) {
    float a = row[n];
    if (a > mx - SEL_CUT) {                  // expected ~1-5 hits per row
      int k = atomicAdd(&cnt[b], 1);
      idx[b * NN + k] = n;
      wv[b * NN + k] = __expf(a - mx) * invl;
    }
  }
}

// ---------- K3: sparse mix + fused final affine -> out ----------
// grid (3 d-chunks, 16 b) x 256 threads; each thread owns one float4 of D.
// Loops over the cnt[b] selected rows (typically 1-5); rows are L3-hot
// from k1's pass. out = (at*mix - x)/bt2.
__global__ __launch_bounds__(256) void k3_sparse(
    const float* __restrict__ images, const float* __restrict__ x,
    const float* __restrict__ svalp, const int* __restrict__ cnt,
    const int* __restrict__ idx, const float* __restrict__ wv,
    float* __restrict__ out)
{
  const int b = blockIdx.y;
  const int d0 = blockIdx.x * 1024 + (threadIdx.x << 2);
  const int c = cnt[b];

  float4 acc = make_float4(0.f, 0.f, 0.f, 0.f);
  for (int j = 0; j < c; ++j) {
    int n = idx[b * NN + j];
    float w = wv[b * NN + j];
    float4 im = *(const float4*)&images[(size_t)n * DD + d0];
    acc.x += w * im.x; acc.y += w * im.y;
    acc.z += w * im.z; acc.w += w * im.w;
  }

  const float sval = *svalp;
  const float at = sqrtf(1.f - sval);
  const float inv_bt2 = 1.f / sval;
  float4 xv = *(const float4*)&x[b * DD + d0];
  float4 o;
  o.x = (at * acc.x - xv.x) * inv_bt2;
  o.y = (at * acc.y - xv.y) * inv_bt2;
  o.z = (at * acc.z - xv.z) * inv_bt2;
  o.w = (at * acc.w - xv.w) * inv_bt2;
  *(float4*)&out[b * DD + d0] = o;
}

extern "C" void kernel_launch(void* const* d_in, const int* in_sizes, int n_in,
                              void* d_out, int out_size, void* d_ws, size_t ws_size,
                              hipStream_t stream) {
  const float* x      = (const float*)d_in[0];
  const float* images = (const float*)d_in[1];
  const float* sval   = (const float*)d_in[2];
  float* out = (float*)d_out;
  float* ws  = (float*)d_ws;

  // ws layout (floats): args[16*10000] | cnt[16] (int) | pad |
  //                     idx[16*10000] (int) | wv[16*10000]
  // total = 480032 floats = 1.92 MB
  float* args = ws;
  int*   cnt  = (int*)(ws + 160000);
  int*   idx  = (int*)(ws + 160032);
  float* wv   = ws + 320032;

  hipLaunchKernelGGL(k1_args, dim3(625), dim3(256), 0, stream,
                     x, images, sval, args);
  hipLaunchKernelGGL(k2_select, dim3(16), dim3(1024), 0, stream,
                     args, cnt, idx, wv);
  hipLaunchKernelGGL(k3_sparse, dim3(3, 16), dim3(256), 0, stream,
                     images, x, sval, cnt, idx, wv, out);
}